// Round 2
// baseline (538.341 us; speedup 1.0000x reference)
//
#include <hip/hip_runtime.h>

#define EPS 1e-7f
#define MAX_NORM (1.0f - 1e-5f)

typedef __attribute__((ext_vector_type(8))) short bf16x8;
typedef __attribute__((ext_vector_type(4))) float f32x4;

__device__ __forceinline__ short f2bf(float f){
  unsigned u = __builtin_bit_cast(unsigned, f);
  u = (u + 0x7fffu + ((u >> 16) & 1u)) >> 16;
  return (short)u;
}

// ---- setup: s = tanh(||b||) * b / ||b||, s_buf[0..255] = s, s_buf[256] = ||s||^2 ----
__global__ void setup_s_kernel(const float* __restrict__ b, float* __restrict__ s_buf){
  __shared__ float redv[256];
  int t = threadIdx.x;
  float v = b[t];
  redv[t] = v * v;
  __syncthreads();
  for (int off = 128; off > 0; off >>= 1){
    if (t < off) redv[t] += redv[t + off];
    __syncthreads();
  }
  float bn = sqrtf(redv[0]);
  float th = tanhf(bn);
  s_buf[t] = th * v / fmaxf(bn, EPS);
  if (t == 0) s_buf[256] = th * th;
}

// ---- setup: W fp32 [256][256] -> bf16 fragment-native layout ----
// element W[n][k] -> chunk ((n>>4)*8 + (k>>5))*64 + ((k>>3)&3)*16 + (n&15), elem k&7
__global__ void conv_w_kernel(const float* __restrict__ W, short* __restrict__ WB){
  int idx = blockIdx.x * 256 + threadIdx.x;
  int n = idx >> 8, k = idx & 255;
  int ks = k >> 5, q = (k >> 3) & 3, j = k & 7;
  int dst = ((((n >> 4) * 8 + ks) * 4 + q) * 16 + (n & 15)) * 8 + j;
  WB[dst] = f2bf(W[idx]);
}

// ---- main fused kernel: barrier-free, LDS-free ----
// Wave owns 16 x-rows (row = blk*64 + wave*16 + l15) x all 256 out cols.
// MFMA: A = W-frag, B = x-frag => D[m=W-row][n=x-row]; lane holds n=l15, m=quad*4+r.
__global__ __launch_bounds__(256, 4)
void hyp_main(const float* __restrict__ x, const short* __restrict__ WB,
              const float* __restrict__ s_buf, float* __restrict__ out){
  const int tid = threadIdx.x;
  const int wave = tid >> 6, lane = tid & 63;
  const int quad = lane >> 4, l15 = lane & 15;
  const int row = blockIdx.x * 64 + wave * 16 + l15;

  // ---- load this lane's x fragments: row l15(+wave*16), cols ks*32 + quad*8 .. +8 ----
  const float* xrow = x + (size_t)row * 256;
  float4 va[8], vb[8];
  #pragma unroll
  for (int ks = 0; ks < 8; ks++){
    const float4* p = (const float4*)(xrow + ks * 32 + quad * 8);
    va[ks] = p[0];
    vb[ks] = p[1];
  }

  // convert to bf16 fragments + accumulate x-norm partial (this lane's 64 k's)
  float xn2 = 0.f;
  bf16x8 xf[8];
  #pragma unroll
  for (int ks = 0; ks < 8; ks++){
    float f0 = va[ks].x, f1 = va[ks].y, f2 = va[ks].z, f3 = va[ks].w;
    float f4 = vb[ks].x, f5 = vb[ks].y, f6 = vb[ks].z, f7 = vb[ks].w;
    xn2 += f0*f0 + f1*f1 + f2*f2 + f3*f3 + f4*f4 + f5*f5 + f6*f6 + f7*f7;
    bf16x8 p;
    p[0]=f2bf(f0); p[1]=f2bf(f1); p[2]=f2bf(f2); p[3]=f2bf(f3);
    p[4]=f2bf(f4); p[5]=f2bf(f5); p[6]=f2bf(f6); p[7]=f2bf(f7);
    xf[ks] = p;
  }
  // reduce over quad dimension -> full ||x_row||^2, replicated in all quads
  xn2 += __shfl_xor(xn2, 16, 64);
  xn2 += __shfl_xor(xn2, 32, 64);

  // ---- K-loop: 16 col-tiles x 8 k-steps ----
  const bf16x8* WBv = (const bf16x8*)WB;
  f32x4 acc[16];
  #pragma unroll
  for (int tn = 0; tn < 16; tn++){
    bf16x8 wf[8];
    #pragma unroll
    for (int ks = 0; ks < 8; ks++)
      wf[ks] = WBv[(tn * 8 + ks) * 64 + lane];
    f32x4 a = (f32x4){0.f, 0.f, 0.f, 0.f};
    #pragma unroll
    for (int ks = 0; ks < 8; ks++)
      a = __builtin_amdgcn_mfma_f32_16x16x32_bf16(wf[ks], xf[ks], a, 0, 0, 0);
    acc[tn] = a;
  }

  // ---- epilogue: per-row reductions (in-wave) ----
  float msq = 0.f, mds = 0.f;
  #pragma unroll
  for (int tn = 0; tn < 16; tn++){
    float4 sv4 = *(const float4*)&s_buf[tn * 16 + quad * 4];
    msq += acc[tn][0]*acc[tn][0] + acc[tn][1]*acc[tn][1]
         + acc[tn][2]*acc[tn][2] + acc[tn][3]*acc[tn][3];
    mds += acc[tn][0]*sv4.x + acc[tn][1]*sv4.y + acc[tn][2]*sv4.z + acc[tn][3]*sv4.w;
  }
  msq += __shfl_xor(msq, 16, 64);
  msq += __shfl_xor(msq, 32, 64);
  mds += __shfl_xor(mds, 16, 64);
  mds += __shfl_xor(mds, 32, 64);

  // per-row scalars (computed redundantly per quad — deterministic, identical)
  float s2 = s_buf[256];
  float xn = fmaxf(sqrtf(xn2), EPS);
  float xc = fminf(xn, 1.0f - 1e-7f);
  float art = 0.5f * (log1pf(xc) - log1pf(-xc));
  float mxn = fmaxf(sqrtf(msq), EPS);
  float tt = tanhf(mxn / xn * art);
  float te = fminf(tt, MAX_NORM);        // proj(res): ||res|| = t
  float sr = te / mxn;                   // res = sr * mx
  float r2 = te * te;
  float xy = sr * mds;                   // <res, s>
  float aa = 1.0f + 2.0f * xy + s2;
  float bc = 1.0f - r2;
  float den = fmaxf(1.0f + 2.0f * xy + r2 * s2, EPS);
  float P = aa * sr / den, Q = bc / den;
  float num2 = aa * aa * r2 + 2.0f * aa * bc * xy + bc * bc * s2;
  float on = fmaxf(sqrtf(num2) / den, EPS);
  if (on > MAX_NORM){ float fsc = MAX_NORM / on; P *= fsc; Q *= fsc; }

  // ---- store: out = P*mx + Q*s, float4 full-line writes ----
  float* orow = out + (size_t)row * 256;
  #pragma unroll
  for (int tn = 0; tn < 16; tn++){
    float4 sv4 = *(const float4*)&s_buf[tn * 16 + quad * 4];
    float4 o;
    o.x = P * acc[tn][0] + Q * sv4.x;
    o.y = P * acc[tn][1] + Q * sv4.y;
    o.z = P * acc[tn][2] + Q * sv4.z;
    o.w = P * acc[tn][3] + Q * sv4.w;
    *(float4*)&orow[tn * 16 + quad * 4] = o;
  }
}

extern "C" void kernel_launch(void* const* d_in, const int* in_sizes, int n_in,
                              void* d_out, int out_size, void* d_ws, size_t ws_size,
                              hipStream_t stream){
  const float* x = (const float*)d_in[0];
  const float* W = (const float*)d_in[1];
  const float* b = (const float*)d_in[2];
  float* out = (float*)d_out;

  short* WB    = (short*)d_ws;                          // 256*256 bf16 = 128 KB
  float* s_buf = (float*)((char*)d_ws + 256 * 256 * 2); // 257 floats

  int N = in_sizes[0] / 256;

  setup_s_kernel<<<1, 256, 0, stream>>>(b, s_buf);
  conv_w_kernel<<<256, 256, 0, stream>>>(W, WB);
  hyp_main<<<N / 64, 256, 0, stream>>>(x, WB, s_buf, out);
}